// Round 6
// baseline (226.889 us; speedup 1.0000x reference)
//
#include <hip/hip_runtime.h>

// BoostedNeuralLDPCDecoder — MI355X HIP implementation (round 10)
//
// Round 9 (fence-free LLC-direct + per-batch barriers) hit 223.5 us total /
// 157 us kernel, VALUBusy 32%. Remaining stall: my inline-asm load helpers
// forced `s_waitcnt vmcnt(0)` + sched_barrier(0) FULL stops after every load
// batch — each CN unit serialized {16 LLC loads -> ~800 cy drain -> compute}.
// Round 10 keeps the protocol but restores compiler-scheduled waits:
//  * all LLC-direct (sc0 sc1) accesses via __hip_atomic_{load,store}
//    (RELAXED, SYSTEM scope) — same encoding (proven by the r9 barrier), but
//    the backend emits counted vmcnt(N) only before first use.
//  * CN: explicit depth-2 pipeline over the 3 (or 2) units per thread:
//    issue(0), issue(1), consume(0), issue(2), consume(1), consume(2).
//    Blocks r<21 have exactly 3 units, r>=21 exactly 2 (uniform per block).
//  * VN: per wave, issue all 4(+1) rows' 8-gathers + xa up front (~40 loads
//    in flight), consume in order; d>8 tail batches issued at consume.
// Barrier, layouts, arithmetic unchanged (absmax 0.0 must be preserved).
//
// Layouts (lane = z => coalesced, incl. shifted circulant access):
//   tot  [N][B][Z] float      (6.68 MB)   — LLC-direct
//   c2v  [E+1][B][Z] int8     (9.07 MB)   — LLC-direct; row E = zero dummy
//   bar  [64 groups][16 uints] (4 KB; one 64 B line per group, 9 used)

#define ITERS 5
#define Nn 68
#define Mm 46
#define Zz 384
#define Ee 368
#define Bb 64
#define Kk 8          // edges per CN (E/M)
#define PADD 24       // padded max VN degree
#define BIGF 1e9f

#define ROWB (Bb*Zz)                     // 24,576 bytes per c2v edge-row
#define TOT_ELEMS (Nn*Bb*Zz)             // 1,671,168 floats
#define C2V_BYTES ((Ee+1)*ROWB)          // 9,068,544 bytes (incl. zero row)
#define TOT_OFF   0
#define C2V_OFF   (TOT_ELEMS*4)          // 6,684,672
#define BAR_OFF   (C2V_OFF + C2V_BYTES)  // 15,753,216; 4 KB of counters
// total ws need: BAR_OFF + 4096 = 15,757,312 bytes

#define BLK 256
#define GBLK 24                          // blocks per group (= per batch b)
#define GROUPS 64                        // one group per b; 24*64 = 1536 blocks
#define CNU (Mm*Zz)                      // 17,664 check-lane units per group
#define STRIDE (GBLK*BLK)                // 6144; STRIDE % Zz == 0
#define OUT_ITER ((size_t)Bb*Zz*Nn)

// ---- LLC-direct (sc0 sc1) accessors: compiler-scheduled, no fences ----
__device__ __forceinline__ float llc_ldf(const float* p) {
    return __hip_atomic_load(p, __ATOMIC_RELAXED, __HIP_MEMORY_SCOPE_SYSTEM);
}
__device__ __forceinline__ int llc_ldb(const signed char* p) {
    return (int)__hip_atomic_load(p, __ATOMIC_RELAXED, __HIP_MEMORY_SCOPE_SYSTEM);
}
__device__ __forceinline__ void llc_stb(signed char* p, int q) {
    __hip_atomic_store(p, (signed char)q, __ATOMIC_RELAXED,
                       __HIP_MEMORY_SCOPE_SYSTEM);
}
__device__ __forceinline__ void llc_stf(float* p, float v) {
    __hip_atomic_store(p, v, __ATOMIC_RELAXED, __HIP_MEMORY_SCOPE_SYSTEM);
}

// ---- per-group barrier: fence-free (round-9, proven) ----
__device__ __forceinline__ void gbar(unsigned* __restrict__ ctr)
{
    __syncthreads();                     // all waves' LLC stores vmcnt-drained
    if (threadIdx.x == 0) {
        __hip_atomic_fetch_add(ctr, 1u, __ATOMIC_RELAXED,
                               __HIP_MEMORY_SCOPE_SYSTEM);
        int spins = 0;
        for (;;) {
            unsigned c = __hip_atomic_load(ctr, __ATOMIC_RELAXED,
                                           __HIP_MEMORY_SCOPE_SYSTEM);
            if (c >= (unsigned)GBLK) break;
            __builtin_amdgcn_s_sleep(2);
            if ((++spins & 31) == 0) {   // RMW valve: coherent by construction
                c = __hip_atomic_fetch_add(ctr, 0u, __ATOMIC_RELAXED,
                                           __HIP_MEMORY_SCOPE_SYSTEM);
                if (c >= (unsigned)GBLK) break;
            }
        }
    }
    __syncthreads();
}

// ---- min-sum tail: round-4 arithmetic, LLC-direct stores ----
__device__ __forceinline__ void minsum_store(
    const float v[Kk], const int off[Kk], float m1, unsigned sflip,
    float w, signed char* __restrict__ c2v)
{
    // min2 over entries whose |v| != min1 (reference tie semantics, BIG if none)
    float m2 = BIGF;
    #pragma unroll
    for (int k = 0; k < Kk; k++) {
        float mag = fabsf(v[k]);
        if (mag != m1) m2 = fminf(m2, mag);
    }
    #pragma unroll
    for (int k = 0; k < Kk; k++) {
        float mag  = fabsf(v[k]);
        float emin = (mag == m1) ? m2 : m1;
        unsigned neg = sflip ^ ((v[k] < 0.0f) ? 1u : 0u);  // csign * own_sign
        float ext = neg ? -emin : emin;
        // _qms5(w * ext): forward == clip(rintf(2*x)/2, +-7.5); store 2*q as int8
        float r = rintf(w * ext * 2.0f);
        r = fminf(15.0f, fmaxf(-15.0f, r));
        llc_stb(c2v + off[k], (int)r);
    }
}

// ---- CN unit: issue 16 loads (no wait) ----
template<bool FIRST>
__device__ __forceinline__ void cn_issue(
    const float* __restrict__ src, const signed char* __restrict__ c2v,
    const int* __restrict__ edge_vn, const int* __restrict__ edge_shift,
    int g, int u, float tv[Kk], int cv[Kk], int off[Kk])
{
    const int cn = __builtin_amdgcn_readfirstlane(u) / Zz;  // wave-uniform
    const int zc = u - cn * Zz;          // per-lane lifted row
    #pragma unroll
    for (int k = 0; k < Kk; k++) {
        int e  = cn + k * Mm;            // edges of this check (edge_cn = e % M)
        int sh = edge_shift[e];          // wave-uniform -> scalar load
        int n  = edge_vn[e];             // wave-uniform
        int z  = zc - sh;
        z += (z >> 31) & Zz;             // mod Z
        int o = e * ROWB + g * Zz + z;
        off[k] = o;
        if (FIRST) {
            tv[k] = src[(g * Nn + n) * Zz + z];  // cached xa; c2v == 0 at it 0
        } else {
            tv[k] = llc_ldf(src + (n * Bb + g) * Zz + z);
            cv[k] = llc_ldb(c2v + o);
        }
    }
}

// ---- CN unit: consume (compiler inserts counted vmcnt before first use) ----
template<bool FIRST>
__device__ __forceinline__ void cn_consume(
    float w, signed char* __restrict__ c2v,
    const float tv[Kk], const int cv[Kk], const int off[Kk])
{
    float v[Kk];
    float m1 = BIGF;
    unsigned sflip = 0u;
    #pragma unroll
    for (int k = 0; k < Kk; k++) {
        float x = FIRST ? tv[k]
                        : (tv[k] - 0.5f * (float)cv[k]);   // one rounding
        x = fminf(20.0f, fmaxf(-20.0f, x));  // allowed_llr_range
        v[k] = x;
        if (x < 0.0f) sflip ^= 1u;
        m1 = fminf(m1, fabsf(x));
    }
    minsum_store(v, off, m1, sflip, w, c2v);
}

// ---- CN phase: depth-2 pipeline over the 3 (or 2) units of this thread ----
// start = r*256+tid < 6144; unit i at start + i*6144 < 17664.
// 3rd unit exists iff start < 5376 = 21*256  ->  r<21: 3 units; r>=21: 2.
template<bool FIRST>
__device__ __forceinline__ void cn_pass(
    const float* __restrict__ src, signed char* __restrict__ c2v,
    const int* __restrict__ edge_vn, const int* __restrict__ edge_shift,
    float w, int g, int r)
{
    const int start = r * BLK + (int)threadIdx.x;
    float tv0[Kk], tv1[Kk], tv2[Kk];
    int   cv0[Kk], cv1[Kk], cv2[Kk];
    int   of0[Kk], of1[Kk], of2[Kk];
    if (r < 21) {
        cn_issue<FIRST>(src, c2v, edge_vn, edge_shift, g, start,            tv0, cv0, of0);
        cn_issue<FIRST>(src, c2v, edge_vn, edge_shift, g, start + STRIDE,   tv1, cv1, of1);
        cn_consume<FIRST>(w, c2v, tv0, cv0, of0);
        cn_issue<FIRST>(src, c2v, edge_vn, edge_shift, g, start + 2*STRIDE, tv2, cv2, of2);
        cn_consume<FIRST>(w, c2v, tv1, cv1, of1);
        cn_consume<FIRST>(w, c2v, tv2, cv2, of2);
    } else {
        cn_issue<FIRST>(src, c2v, edge_vn, edge_shift, g, start,            tv0, cv0, of0);
        cn_issue<FIRST>(src, c2v, edge_vn, edge_shift, g, start + STRIDE,   tv1, cv1, of1);
        cn_consume<FIRST>(w, c2v, tv0, cv0, of0);
        cn_consume<FIRST>(w, c2v, tv1, cv1, of1);
    }
}

// ---- VN row: issue first 8 gathers + xa (no wait) ----
__device__ __forceinline__ void vn_issue_row(
    const signed char* __restrict__ c2v, const float* __restrict__ xa,
    const int* __restrict__ sdeg, const int* __restrict__ svoff,
    int g, int z, int bz, int n0, int row,
    int q[8], float* xv, int* dn, int* dd)
{
    int n = __builtin_amdgcn_readfirstlane(n0 + row);
    int d = __builtin_amdgcn_readfirstlane(sdeg[n]);
    const int* vo = svoff + n * PADD;    // LDS broadcast
    #pragma unroll
    for (int j = 0; j < 8; j++) q[j] = llc_ldb(c2v + (vo[j] + bz));
    *xv = xa[(size_t)(g * Nn + n) * Zz + z];
    *dn = n; *dd = d;
}

// ---- VN row: consume; rare d>8 tail batches issued here ----
__device__ __forceinline__ float vn_consume_row(
    const signed char* __restrict__ c2v, const int* __restrict__ svoff,
    int bz, int n, int d, const int q[8], float xv)
{
    int acc = 0;                         // sum of int8 messages (2x): exact
    if (d > 8) {
        const int* vo = svoff + n * PADD;
        int q1[8];
        #pragma unroll
        for (int j = 0; j < 8; j++) q1[j] = llc_ldb(c2v + (vo[8 + j] + bz));
        if (d > 16) {
            int q2[8];
            #pragma unroll
            for (int j = 0; j < 8; j++) q2[j] = llc_ldb(c2v + (vo[16 + j] + bz));
            #pragma unroll
            for (int j = 0; j < 8; j++) acc += q[j];   // ready; hides q1/q2 wait
            #pragma unroll
            for (int j = 0; j < 8; j++) acc += q1[j];
            #pragma unroll
            for (int j = 0; j < 8; j++) acc += q2[j];
        } else {
            #pragma unroll
            for (int j = 0; j < 8; j++) acc += q[j];
            #pragma unroll
            for (int j = 0; j < 8; j++) acc += q1[j];
        }
    } else {
        #pragma unroll
        for (int j = 0; j < 8; j++) acc += q[j];
    }
    return xv + 0.5f * (float)acc;
}

// ---- VN phase: one 17x64 tile per block; issue-all-then-consume per wave ----
__device__ __forceinline__ void vn_pass(
    const float* __restrict__ xa, const signed char* __restrict__ c2v,
    float* __restrict__ tot, float* __restrict__ out_it,
    const int* __restrict__ sdeg, const int* __restrict__ svoff,
    int write_tot, float (*tile)[65], int g, int r)
{
    const int wave = threadIdx.x >> 6;
    const int lane = threadIdx.x & 63;
    const int zq = r >> 2, nc = r & 3;   // 24 = 6 z-quads x 4 n-chunks
    const int z0 = zq * 64, n0 = nc * 17;
    const int z  = z0 + lane;
    const int bz = g * Zz + z;           // offset within a c2v edge-row

    // rows wave, wave+4, wave+8, wave+12 for all waves; row 16 on wave 0
    int q[4][8]; float xv[4]; int dn[4], dd[4];
    #pragma unroll
    for (int t = 0; t < 4; t++)
        vn_issue_row(c2v, xa, sdeg, svoff, g, z, bz, n0, wave + 4 * t,
                     q[t], &xv[t], &dn[t], &dd[t]);
    int q4[8]; float xv4 = 0.0f; int dn4 = 0, dd4 = 0;
    const bool has5 = (wave == 0);
    if (has5)
        vn_issue_row(c2v, xa, sdeg, svoff, g, z, bz, n0, 16,
                     q4, &xv4, &dn4, &dd4);

    #pragma unroll
    for (int t = 0; t < 4; t++) {
        float s = vn_consume_row(c2v, svoff, bz, dn[t], dd[t], q[t], xv[t]);
        if (write_tot) llc_stf(tot + (dn[t] * Bb + g) * Zz + z, s);
        tile[wave + 4 * t][lane] = s;
    }
    if (has5) {
        float s = vn_consume_row(c2v, svoff, bz, dn4, dd4, q4, xv4);
        if (write_tot) llc_stf(tot + (dn4 * Bb + g) * Zz + z, s);
        tile[16][lane] = s;
    }
    __syncthreads();

    // out[it][b][z][n]: 64 z-rows x 17 contiguous floats (68 B segments);
    // normal cached stores (no in-kernel reader; kernel-end flush publishes)
    float* dst = out_it + ((size_t)g * Zz + z0) * Nn + n0;
    for (int idx = threadIdx.x; idx < 17 * 64; idx += BLK) {
        int zz = idx / 17;
        int nn = idx - zz * 17;
        dst[(size_t)zz * Nn + nn] = tile[nn][zz];
    }
    __syncthreads();                     // tile protected before any reuse
}

__global__ __launch_bounds__(BLK, 6) void fused_kernel(
    const float* __restrict__ xa, const float* __restrict__ cn_weight,
    const int* __restrict__ edge_vn, const int* __restrict__ edge_shift,
    float* __restrict__ tot, signed char* __restrict__ c2v,
    unsigned* __restrict__ bar, float* __restrict__ out)
{
    __shared__ float tile[17][65];       // [n_local][z_local+1 pad]
    __shared__ int   svoff[Nn * PADD];   // per-VN byte offsets (dummy-padded)
    __shared__ int   sdeg[Nn];

    const int r = blockIdx.x;            // rank within group [0, 24)
    const int g = blockIdx.y;            // group = batch b   [0, 64)

    // ---- per-block LDS gather tables (order-independent -> bit-exact) ----
    for (int i = threadIdx.x; i < Nn; i += BLK) sdeg[i] = 0;
    for (int i = threadIdx.x; i < Nn * PADD; i += BLK) svoff[i] = Ee * ROWB;
    __syncthreads();
    for (int e = threadIdx.x; e < Ee; e += BLK) {
        int n = edge_vn[e];
        int slot = atomicAdd(&sdeg[n], 1);
        if (slot < PADD) svoff[n * PADD + slot] = e * ROWB;
    }
    // ---- zero this group's 384 B dummy-row slice (LLC-direct, read LLC) ----
    if (r == 0) {
        int* p = (int*)(c2v + (size_t)Ee * ROWB + g * Zz);
        for (int i = threadIdx.x; i < Zz / 4; i += BLK)
            __hip_atomic_store(p + i, 0, __ATOMIC_RELAXED,
                               __HIP_MEMORY_SCOPE_SYSTEM);
    }
    __syncthreads();                     // tables ready; zeros drain by bar 0

    unsigned* gb = bar + g * 16;         // this group's 64 B counter line

    for (int it = 0; it < ITERS; ++it) {
        const float w = cn_weight[it];
        if (it == 0) cn_pass<true >(xa,  c2v, edge_vn, edge_shift, w, g, r);
        else         cn_pass<false>(tot, c2v, edge_vn, edge_shift, w, g, r);
        gbar(gb + 2 * it);                           // group's c2v slice ready
        vn_pass(xa, c2v, tot, out + (size_t)it * OUT_ITER,
                sdeg, svoff, (it != ITERS - 1) ? 1 : 0, tile, g, r);
        if (it != ITERS - 1) gbar(gb + 2 * it + 1);  // group's tot slice ready
    }
}

extern "C" void kernel_launch(void* const* d_in, const int* in_sizes, int n_in,
                              void* d_out, int out_size, void* d_ws, size_t ws_size,
                              hipStream_t stream) {
    const float* xa        = (const float*)d_in[0];  // [B][N][Z]
    const float* cn_weight = (const float*)d_in[1];  // [ITERS]
    const int*   edge_vn   = (const int*)d_in[2];    // [E]
    // d_in[3] = edge_cn: structurally e % M, not needed
    const int*   edge_shift= (const int*)d_in[4];    // [E]
    float* out = (float*)d_out;                      // [ITERS][B][Z][N]

    char* ws = (char*)d_ws;
    float*       tot = (float*)(ws + TOT_OFF);
    signed char* c2v = (signed char*)(ws + C2V_OFF);
    unsigned*    bar = (unsigned*)(ws + BAR_OFF);

    // zero the 64 x 64 B barrier lines — capture-safe, re-poison-proof
    hipMemsetAsync(ws + BAR_OFF, 0, GROUPS * 64, stream);

    fused_kernel<<<dim3(GBLK, GROUPS), dim3(BLK), 0, stream>>>(
        xa, cn_weight, edge_vn, edge_shift, tot, c2v, bar, out);
}